// Round 1
// baseline (132158.655 us; speedup 1.0000x reference)
//
#include <hip/hip_runtime.h>

#define T_STEPS 128
#define B_SIZE  32768
#define F_DIM   8
#define H_DIM   64
#define R_DIM   192   // 3*H

#define BLOCK_THREADS 512
#define SAMPLES_PER_BLOCK (BLOCK_THREADS / 8)          // 64
#define GRID_BLOCKS (B_SIZE / SAMPLES_PER_BLOCK)       // 512

static_assert(B_SIZE % SAMPLES_PER_BLOCK == 0, "grid must tile batch exactly");

__device__ __forceinline__ float fast_sigmoid(float x) {
    x = fminf(fmaxf(x, -30.f), 30.f);
    return __builtin_amdgcn_rcpf(1.f + __expf(-x));
}
__device__ __forceinline__ float fast_tanh(float x) {
    x = fminf(fmaxf(x, -15.f), 15.f);
    const float e = __expf(2.f * x);
    return (e - 1.f) * __builtin_amdgcn_rcpf(e + 1.f);
}

// ds_swizzle BitMode: newlane = ((lane & and) | or) ^ xor ; imm = (xor<<10)|(or<<5)|and
// broadcast lane C within each group of 8: and=0x18, or=C, xor=0
template<int C>
__device__ __forceinline__ float bcast8(float v) {
    return __int_as_float(__builtin_amdgcn_ds_swizzle(__float_as_int(v), (C << 5) | 0x18));
}
// xor-swizzle across lanes (within group of 8 for XM in {1,2,4}): and=0x1F, xor=XM
template<int XM>
__device__ __forceinline__ float xswz(float v) {
    return __int_as_float(__builtin_amdgcn_ds_swizzle(__float_as_int(v), (XM << 10) | 0x1F));
}

__device__ __forceinline__ void fma8(float (&a)[8], const float s, const float4 v0, const float4 v1) {
    a[0] += s * v0.x; a[1] += s * v0.y; a[2] += s * v0.z; a[3] += s * v0.w;
    a[4] += s * v1.x; a[5] += s * v1.y; a[6] += s * v1.z; a[7] += s * v1.w;
}
__device__ __forceinline__ void set8(float (&a)[8], const float4 v0, const float4 v1) {
    a[0] = v0.x; a[1] = v0.y; a[2] = v0.z; a[3] = v0.w;
    a[4] = v1.x; a[5] = v1.y; a[6] = v1.z; a[7] = v1.w;
}
__device__ __forceinline__ float4 ld4(const float* p) { return *(const float4*)p; }

// One owner-oct block of the h @ Whh^T contribution: k = KO*8 + m2, static reg index m2.
template<int KO>
__device__ __forceinline__ void h_block(const float (&h)[8], float (&ar)[8], float (&az)[8], float (&anh)[8],
                                        const float* __restrict__ sWhh, const int jb) {
#pragma unroll
    for (int m2 = 0; m2 < 8; ++m2) {
        const int k = KO * 8 + m2;
        const float hk = bcast8<KO>(h[m2]);
        const float* row = sWhh + k * R_DIM + jb;
        const float4 r0 = ld4(row);       const float4 r1 = ld4(row + 4);
        const float4 z0 = ld4(row + 64);  const float4 z1 = ld4(row + 68);
        const float4 n0 = ld4(row + 128); const float4 n1 = ld4(row + 132);
        fma8(ar,  hk, r0, r1);
        fma8(az,  hk, z0, z1);
        fma8(anh, hk, n0, n1);
    }
}

__device__ __forceinline__ void gru_step(float (&h)[8], const float (&x)[8],
                                         const float* __restrict__ sWih, const float* __restrict__ sWhh,
                                         const float* __restrict__ sBrz, const float* __restrict__ sBni,
                                         const float* __restrict__ sBnh, const int jb) {
    float ar[8], az[8], ani[8], anh[8];
    set8(ar,  ld4(sBrz + jb),      ld4(sBrz + jb + 4));
    set8(az,  ld4(sBrz + 64 + jb), ld4(sBrz + 64 + jb + 4));
    set8(ani, ld4(sBni + jb),      ld4(sBni + jb + 4));
    set8(anh, ld4(sBnh + jb),      ld4(sBnh + jb + 4));

    // x @ Wih^T : k = 0..7 (ani gets the x-side n contribution)
#pragma unroll
    for (int k = 0; k < F_DIM; ++k) {
        const float xk = x[k];
        const float* row = sWih + k * R_DIM + jb;
        const float4 r0 = ld4(row);       const float4 r1 = ld4(row + 4);
        const float4 z0 = ld4(row + 64);  const float4 z1 = ld4(row + 68);
        const float4 n0 = ld4(row + 128); const float4 n1 = ld4(row + 132);
        fma8(ar,  xk, r0, r1);
        fma8(az,  xk, z0, z1);
        fma8(ani, xk, n0, n1);
    }

    // h @ Whh^T : k = 0..63, owner oct = k>>3 broadcasts its h
    h_block<0>(h, ar, az, anh, sWhh, jb);
    h_block<1>(h, ar, az, anh, sWhh, jb);
    h_block<2>(h, ar, az, anh, sWhh, jb);
    h_block<3>(h, ar, az, anh, sWhh, jb);
    h_block<4>(h, ar, az, anh, sWhh, jb);
    h_block<5>(h, ar, az, anh, sWhh, jb);
    h_block<6>(h, ar, az, anh, sWhh, jb);
    h_block<7>(h, ar, az, anh, sWhh, jb);

#pragma unroll
    for (int m = 0; m < 8; ++m) {
        const float r = fast_sigmoid(ar[m]);
        const float z = fast_sigmoid(az[m]);
        const float n = fast_tanh(ani[m] + r * anh[m]);
        h[m] = n + z * (h[m] - n);   // (1-z)*n + z*h
    }
}

__global__ __launch_bounds__(BLOCK_THREADS, 2)
void seq2seq_gru_kernel(const float* __restrict__ inputs, const float* __restrict__ target,
                        const float* __restrict__ eWih, const float* __restrict__ eWhh,
                        const float* __restrict__ ebih, const float* __restrict__ ebhh,
                        const float* __restrict__ dWih, const float* __restrict__ dWhh,
                        const float* __restrict__ dbih, const float* __restrict__ dbhh,
                        const float* __restrict__ oW, const float* __restrict__ ob,
                        float* __restrict__ out)
{
    // Transposed weight tiles: sWih[k][j] (8x192), sWhh[k][j] (64x192), sWo[k][f] (64x8)
    __shared__ __align__(16) float sWih[F_DIM * R_DIM];
    __shared__ __align__(16) float sWhh[H_DIM * R_DIM];
    __shared__ __align__(16) float sBrz[2 * H_DIM];   // bih+bhh for r,z rows
    __shared__ __align__(16) float sBni[H_DIM];       // bih n-rows
    __shared__ __align__(16) float sBnh[H_DIM];       // bhh n-rows
    __shared__ __align__(16) float sWo[H_DIM * F_DIM];
    __shared__ __align__(16) float sBo[F_DIM];

    const int tid = threadIdx.x;
    const int oct = tid & 7;
    const int jb  = oct * 8;
    const long b  = (long)blockIdx.x * SAMPLES_PER_BLOCK + (tid >> 3);

    // ---- stage output projection (once) + encoder weights ----
    for (int idx = tid; idx < H_DIM * F_DIM; idx += BLOCK_THREADS) {
        const int f = idx >> 6, k = idx & 63;
        sWo[k * F_DIM + f] = oW[idx];
    }
    if (tid < F_DIM) sBo[tid] = ob[tid];
    for (int idx = tid; idx < R_DIM * F_DIM; idx += BLOCK_THREADS) {
        const int j = idx >> 3, k = idx & 7;
        sWih[k * R_DIM + j] = eWih[idx];
    }
    for (int idx = tid; idx < R_DIM * H_DIM; idx += BLOCK_THREADS) {
        const int j = idx >> 6, k = idx & 63;
        sWhh[k * R_DIM + j] = eWhh[idx];
    }
    for (int j = tid; j < 2 * H_DIM; j += BLOCK_THREADS) sBrz[j] = ebih[j] + ebhh[j];
    for (int i = tid; i < H_DIM; i += BLOCK_THREADS) {
        sBni[i] = ebih[2 * H_DIM + i];
        sBnh[i] = ebhh[2 * H_DIM + i];
    }
    __syncthreads();

    float h[8];
#pragma unroll
    for (int m = 0; m < 8; ++m) h[m] = 0.f;
    float x[8];

    // ---- encoder ----
#pragma unroll 1
    for (int t = 0; t < T_STEPS; ++t) {
        const float* xp = inputs + ((long)t * B_SIZE + b) * F_DIM;
        const float4 xa = ld4(xp);
        const float4 xb = ld4(xp + 4);
        set8(x, xa, xb);
        gru_step(h, x, sWih, sWhh, sBrz, sBni, sBnh, jb);
    }

    // ---- swap to decoder weights ----
    __syncthreads();
    for (int idx = tid; idx < R_DIM * F_DIM; idx += BLOCK_THREADS) {
        const int j = idx >> 3, k = idx & 7;
        sWih[k * R_DIM + j] = dWih[idx];
    }
    for (int idx = tid; idx < R_DIM * H_DIM; idx += BLOCK_THREADS) {
        const int j = idx >> 6, k = idx & 63;
        sWhh[k * R_DIM + j] = dWhh[idx];
    }
    for (int j = tid; j < 2 * H_DIM; j += BLOCK_THREADS) sBrz[j] = dbih[j] + dbhh[j];
    for (int i = tid; i < H_DIM; i += BLOCK_THREADS) {
        sBni[i] = dbih[2 * H_DIM + i];
        sBnh[i] = dbhh[2 * H_DIM + i];
    }
    __syncthreads();

    // ---- decoder (teacher forcing: x_0 = 0, x_t = target[t-1]) ----
#pragma unroll 1
    for (int t = 0; t < T_STEPS; ++t) {
        if (t == 0) {
#pragma unroll
            for (int m = 0; m < 8; ++m) x[m] = 0.f;
        } else {
            const float* xp = target + ((long)(t - 1) * B_SIZE + b) * F_DIM;
            const float4 xa = ld4(xp);
            const float4 xb = ld4(xp + 4);
            set8(x, xa, xb);
        }
        gru_step(h, x, sWih, sWhh, sBrz, sBni, sBnh, jb);

        // y = h_new @ oW^T + ob ; each lane sums its 8 k's, then 8-lane xor reduce
        float y[8];
#pragma unroll
        for (int f = 0; f < 8; ++f) y[f] = 0.f;
#pragma unroll
        for (int m = 0; m < 8; ++m) {
            const int k = jb + m;
            const float4 w0 = ld4(sWo + k * F_DIM);
            const float4 w1 = ld4(sWo + k * F_DIM + 4);
            y[0] += h[m] * w0.x; y[1] += h[m] * w0.y; y[2] += h[m] * w0.z; y[3] += h[m] * w0.w;
            y[4] += h[m] * w1.x; y[5] += h[m] * w1.y; y[6] += h[m] * w1.z; y[7] += h[m] * w1.w;
        }
#pragma unroll
        for (int f = 0; f < 8; ++f) {
            y[f] += xswz<1>(y[f]);
            y[f] += xswz<2>(y[f]);
            y[f] += xswz<4>(y[f]);
        }
        if (oct == 0) {
            float* op = out + ((long)t * B_SIZE + b) * F_DIM;
            const float4 o0 = make_float4(y[0] + sBo[0], y[1] + sBo[1], y[2] + sBo[2], y[3] + sBo[3]);
            const float4 o1 = make_float4(y[4] + sBo[4], y[5] + sBo[5], y[6] + sBo[6], y[7] + sBo[7]);
            *(float4*)op = o0;
            *(float4*)(op + 4) = o1;
        }
    }
}

extern "C" void kernel_launch(void* const* d_in, const int* in_sizes, int n_in,
                              void* d_out, int out_size, void* d_ws, size_t ws_size,
                              hipStream_t stream) {
    (void)in_sizes; (void)n_in; (void)d_ws; (void)ws_size; (void)out_size;
    const float* inputs = (const float*)d_in[0];
    const float* target = (const float*)d_in[1];
    const float* eWih   = (const float*)d_in[2];
    const float* eWhh   = (const float*)d_in[3];
    const float* ebih   = (const float*)d_in[4];
    const float* ebhh   = (const float*)d_in[5];
    const float* dWih   = (const float*)d_in[6];
    const float* dWhh   = (const float*)d_in[7];
    const float* dbih   = (const float*)d_in[8];
    const float* dbhh   = (const float*)d_in[9];
    const float* oW     = (const float*)d_in[10];
    const float* ob     = (const float*)d_in[11];
    float* out = (float*)d_out;

    seq2seq_gru_kernel<<<dim3(GRID_BLOCKS), dim3(BLOCK_THREADS), 0, stream>>>(
        inputs, target, eWih, eWhh, ebih, ebhh, dWih, dWhh, dbih, dbhh, oW, ob, out);
}

// Round 2
// 576.630 us; speedup vs baseline: 229.1914x; 229.1914x over previous
//
#include <hip/hip_runtime.h>

#define T_STEPS 128
#define B_SIZE  32768
#define F_DIM   8
#define H_DIM   64

#define BLOCK_THREADS 256
#define WAVES_PER_BLOCK 4
#define SAMPLES_PER_WAVE 16
#define GRID_BLOCKS (B_SIZE / (WAVES_PER_BLOCK * SAMPLES_PER_WAVE))   // 512

typedef float f32x4 __attribute__((ext_vector_type(4)));
typedef short bfrag __attribute__((ext_vector_type(8)));   // 8 bf16 bit patterns (4 VGPRs)

#define MFMA16(A, B, C) __builtin_amdgcn_mfma_f32_16x16x32_bf16((A), (B), (C), 0, 0, 0)

__device__ __forceinline__ short f2bf(float f) {
    return __builtin_bit_cast(short, (__bf16)f);
}
__device__ __forceinline__ float sigf(float x) {
    // 1/(1+e^-x): e^-x -> inf => rcp -> 0 ; e^-x -> 0 => 1. No clamp needed.
    return __builtin_amdgcn_rcpf(1.f + __expf(-x));
}
__device__ __forceinline__ float tanhf_fast(float x) {
    x = fminf(fmaxf(x, -15.f), 15.f);
    const float e = __expf(2.f * x);
    return 1.f - 2.f * __builtin_amdgcn_rcpf(e + 1.f);
}

// All weight fragments live in registers (A-operand of the transposed GEMM).
// Gate rows: [0,64) = r, [64,128) = z, [128,192) = n.
// K layout: kt0 = h[0..31], kt1 = h[32..63], x-ktile: k<8 = x, k==8 = bias row, else 0.
struct Frags {
    bfrag wr[4][3];    // r-gate tiles: 2 h-ktiles + 1 x-ktile (bias row = bih+bhh)
    bfrag wz[4][3];    // z-gate tiles
    bfrag whn[4][2];   // n-gate h-side (separate accumulator; r multiplies this)
    bfrag win[4];      // n-gate x-side (bias row = bih)
    f32x4 bhn[4];      // bhh n-rows, per-lane at u = 16*tt + 4*g + reg
};

__device__ __forceinline__ void load_phase(Frags& F, const float* __restrict__ Wih,
                                           const float* __restrict__ Whh,
                                           const float* __restrict__ bih,
                                           const float* __restrict__ bhh,
                                           const int c, const int g) {
#pragma unroll
    for (int tt = 0; tt < 4; ++tt) {
        const int rowR = 16 * tt + c;
        const int rowZ = 64 + rowR;
        const int rowN = 128 + rowR;
        // h k-tiles: A[m=row][k], lane elem e -> k = 32*kt + 16*(e>>2) + 4*g + (e&3)
#pragma unroll
        for (int kt = 0; kt < 2; ++kt) {
#pragma unroll
            for (int eh = 0; eh < 2; ++eh) {
#pragma unroll
                for (int ep = 0; ep < 2; ++ep) {
                    const int e = 4 * eh + 2 * ep;
                    const int k = 32 * kt + 16 * eh + 4 * g + 2 * ep;
                    const float2 vR = *(const float2*)(Whh + rowR * H_DIM + k);
                    const float2 vZ = *(const float2*)(Whh + rowZ * H_DIM + k);
                    const float2 vN = *(const float2*)(Whh + rowN * H_DIM + k);
                    F.wr[tt][kt][e]     = f2bf(vR.x);
                    F.wr[tt][kt][e + 1] = f2bf(vR.y);
                    F.wz[tt][kt][e]     = f2bf(vZ.x);
                    F.wz[tt][kt][e + 1] = f2bf(vZ.y);
                    F.whn[tt][kt][e]     = f2bf(vN.x);
                    F.whn[tt][kt][e + 1] = f2bf(vN.y);
                }
            }
        }
        // x k-tile: k<8 -> Wih, k==8 -> bias row, else 0
#pragma unroll
        for (int e = 0; e < 8; ++e) {
            const int k = 16 * (e >> 2) + 4 * g + (e & 3);
            float vR = 0.f, vZ = 0.f, vN = 0.f;
            if (k < 8) {
                vR = Wih[rowR * F_DIM + k];
                vZ = Wih[rowZ * F_DIM + k];
                vN = Wih[rowN * F_DIM + k];
            } else if (k == 8) {
                vR = bih[rowR] + bhh[rowR];
                vZ = bih[rowZ] + bhh[rowZ];
                vN = bih[rowN];
            }
            F.wr[tt][2][e] = f2bf(vR);
            F.wz[tt][2][e] = f2bf(vZ);
            F.win[tt][e]   = f2bf(vN);
        }
#pragma unroll
        for (int r = 0; r < 4; ++r)
            F.bhn[tt][r] = bhh[128 + 16 * tt + 4 * g + r];
    }
}

// h (C'-layout, f32) -> B-fragments for next MFMA. Entirely lane-local:
// hB[kt] elem e corresponds to u = 32*kt + 16*(e>>2) + 4*g + (e&3)
// hc[tt][reg]    corresponds to u = 16*tt + 4*g + reg   => tt = 2*kt + (e>>2), reg = e&3.
__device__ __forceinline__ void build_hB(bfrag (&hB)[2], const f32x4 (&hc)[4]) {
#pragma unroll
    for (int kt = 0; kt < 2; ++kt)
#pragma unroll
        for (int e = 0; e < 8; ++e)
            hB[kt][e] = f2bf(hc[2 * kt + (e >> 2)][e & 3]);
}

__device__ __forceinline__ void gru_step_m(const Frags& F, const bfrag (&hB)[2],
                                           const bfrag bx, f32x4 (&hc)[4]) {
#pragma unroll
    for (int tt = 0; tt < 4; ++tt) {
        f32x4 aR  = {0.f, 0.f, 0.f, 0.f};
        f32x4 aZ  = {0.f, 0.f, 0.f, 0.f};
        f32x4 aIN = {0.f, 0.f, 0.f, 0.f};
        f32x4 aHN = {0.f, 0.f, 0.f, 0.f};
        aR = MFMA16(F.wr[tt][0], hB[0], aR);
        aR = MFMA16(F.wr[tt][1], hB[1], aR);
        aR = MFMA16(F.wr[tt][2], bx,    aR);
        aZ = MFMA16(F.wz[tt][0], hB[0], aZ);
        aZ = MFMA16(F.wz[tt][1], hB[1], aZ);
        aZ = MFMA16(F.wz[tt][2], bx,    aZ);
        aHN = MFMA16(F.whn[tt][0], hB[0], aHN);
        aHN = MFMA16(F.whn[tt][1], hB[1], aHN);
        aIN = MFMA16(F.win[tt], bx, aIN);
#pragma unroll
        for (int r = 0; r < 4; ++r) {
            const float rg = sigf(aR[r]);
            const float zg = sigf(aZ[r]);
            const float ng = tanhf_fast(aIN[r] + rg * (aHN[r] + F.bhn[tt][r]));
            hc[tt][r] = ng + zg * (hc[tt][r] - ng);   // (1-z)*n + z*h
        }
    }
}

__device__ __forceinline__ bfrag make_bx(const float4 xv) {
    bfrag bx;
#pragma unroll
    for (int e = 0; e < 4; ++e) bx[e] = f2bf(((const float*)&xv)[e]);
#pragma unroll
    for (int e = 4; e < 8; ++e) bx[e] = f2bf(0.f);
    return bx;
}

__global__ __launch_bounds__(BLOCK_THREADS, 2)
void seq2seq_mfma_kernel(const float* __restrict__ inputs, const float* __restrict__ target,
                         const float* __restrict__ eWih, const float* __restrict__ eWhh,
                         const float* __restrict__ ebih, const float* __restrict__ ebhh,
                         const float* __restrict__ dWih, const float* __restrict__ dWhh,
                         const float* __restrict__ dbih, const float* __restrict__ dbhh,
                         const float* __restrict__ oW, const float* __restrict__ ob,
                         float* __restrict__ out)
{
    const int tid  = threadIdx.x;
    const int lane = tid & 63;
    const int wv   = tid >> 6;
    const int c    = lane & 15;   // sample col within tile / A m-index
    const int g    = lane >> 4;   // lane group
    const long samp = ((long)blockIdx.x * WAVES_PER_BLOCK + wv) * SAMPLES_PER_WAVE + c;

    Frags F;
    load_phase(F, eWih, eWhh, ebih, ebhh, c, g);

    // x B-frag constant part: lane group 2 carries the bias-1 row (k==8)
    const float4 xconst = (g == 2) ? make_float4(1.f, 0.f, 0.f, 0.f)
                                   : make_float4(0.f, 0.f, 0.f, 0.f);

    f32x4 hc[4];
#pragma unroll
    for (int tt = 0; tt < 4; ++tt) hc[tt] = (f32x4){0.f, 0.f, 0.f, 0.f};
    bfrag hB[2];
    build_hB(hB, hc);   // h0 = 0

    // ---------------- encoder ----------------
    float4 xn = xconst;
    if (g < 2) xn = *(const float4*)(inputs + samp * F_DIM + 4 * g);
#pragma unroll 1
    for (int t = 0; t < T_STEPS; ++t) {
        const float4 xv = xn;
        if (g < 2) {  // prefetch next step's x (hide HBM latency under this step)
            const int tn = (t + 1 < T_STEPS) ? t + 1 : t;
            xn = *(const float4*)(inputs + ((long)tn * B_SIZE + samp) * F_DIM + 4 * g);
        }
        const bfrag bx = make_bx(xv);
        gru_step_m(F, hB, bx, hc);
        build_hB(hB, hc);
    }

    // ---------------- decoder ----------------
    load_phase(F, dWih, dWhh, dbih, dbhh, c, g);

    bfrag wout[2];
#pragma unroll
    for (int kt = 0; kt < 2; ++kt)
#pragma unroll
        for (int e = 0; e < 8; ++e) {
            const int k = 32 * kt + 16 * (e >> 2) + 4 * g + (e & 3);
            wout[kt][e] = f2bf((c < F_DIM) ? oW[c * H_DIM + k] : 0.f);
        }
    f32x4 obv;
#pragma unroll
    for (int r = 0; r < 4; ++r) obv[r] = (g < 2) ? ob[4 * g + r] : 0.f;

    // decoder input: x_0 = 0, x_t = target[t-1]
    xn = (g < 2) ? make_float4(0.f, 0.f, 0.f, 0.f) : xconst;
#pragma unroll 1
    for (int t = 0; t < T_STEPS; ++t) {
        const float4 xv = xn;
        if (g < 2 && t + 1 < T_STEPS) {  // x_{t+1} = target[t]
            xn = *(const float4*)(target + ((long)t * B_SIZE + samp) * F_DIM + 4 * g);
        }
        const bfrag bx = make_bx(xv);
        gru_step_m(F, hB, bx, hc);
        build_hB(hB, hc);   // h_new: feeds out-proj now and next step's GEMM

        // y^T = oW . h^T : C' row = f (=4g+reg, valid for g<2), col = sample
        f32x4 aO = {0.f, 0.f, 0.f, 0.f};
        aO = MFMA16(wout[0], hB[0], aO);
        aO = MFMA16(wout[1], hB[1], aO);
        if (g < 2) {
            float4 o;
            o.x = aO[0] + obv[0];
            o.y = aO[1] + obv[1];
            o.z = aO[2] + obv[2];
            o.w = aO[3] + obv[3];
            *(float4*)(out + ((long)t * B_SIZE + samp) * F_DIM + 4 * g) = o;
        }
    }
}

extern "C" void kernel_launch(void* const* d_in, const int* in_sizes, int n_in,
                              void* d_out, int out_size, void* d_ws, size_t ws_size,
                              hipStream_t stream) {
    (void)in_sizes; (void)n_in; (void)d_ws; (void)ws_size; (void)out_size;
    const float* inputs = (const float*)d_in[0];
    const float* target = (const float*)d_in[1];
    const float* eWih   = (const float*)d_in[2];
    const float* eWhh   = (const float*)d_in[3];
    const float* ebih   = (const float*)d_in[4];
    const float* ebhh   = (const float*)d_in[5];
    const float* dWih   = (const float*)d_in[6];
    const float* dWhh   = (const float*)d_in[7];
    const float* dbih   = (const float*)d_in[8];
    const float* dbhh   = (const float*)d_in[9];
    const float* oW     = (const float*)d_in[10];
    const float* ob     = (const float*)d_in[11];
    float* out = (float*)d_out;

    seq2seq_mfma_kernel<<<dim3(GRID_BLOCKS), dim3(BLOCK_THREADS), 0, stream>>>(
        inputs, target, eWih, eWhh, ebih, ebhh, dWih, dWhh, dbih, dbhh, oW, ob, out);
}

// Round 3
// 479.300 us; speedup vs baseline: 275.7327x; 1.2031x over previous
//
#include <hip/hip_runtime.h>

#define T_STEPS 128
#define B_SIZE  32768
#define F_DIM   8
#define H_DIM   64

#define BLOCK_THREADS 128                 // 2 waves = one 16-sample team
#define GRID_BLOCKS   (B_SIZE / 16)       // 2048

typedef float f32x4 __attribute__((ext_vector_type(4)));
typedef short bfrag __attribute__((ext_vector_type(8)));   // 8 bf16 (4 VGPRs)
typedef unsigned int u32x4 __attribute__((ext_vector_type(4)));

#define MFMA16(A, B, C) __builtin_amdgcn_mfma_f32_16x16x32_bf16((A), (B), (C), 0, 0, 0)

__device__ __forceinline__ short f2bf(float f) { return __builtin_bit_cast(short, (__bf16)f); }
__device__ __forceinline__ float4 ld4(const void* p) { return *(const float4*)p; }

constexpr float S1 = 1.4426950408889634f;  // log2(e)  -> folded into r,z weights
constexpr float S2 = 2.f * S1;             // 2*log2(e)-> folded into n weights

// Layout relations (verified by round-2 pass):
//  A/B frag elem e -> k = 32*kt + 16*(e>>2) + 4*g + (e&3), A row / B col = lane&15
//  C/D: col = lane&15 (sample), row = 4*g + reg  (tile tt covers rows 16*tt..16*tt+15)
// Split: wave w owns tt in {2w, 2w+1}  == h-units [32w,32w+32) == B k-tile kt=w.

__global__ __launch_bounds__(BLOCK_THREADS, 3)
void seq2seq_split_kernel(const float* __restrict__ inputs, const float* __restrict__ target,
                          const float* __restrict__ eWih, const float* __restrict__ eWhh,
                          const float* __restrict__ ebih, const float* __restrict__ ebhh,
                          const float* __restrict__ dWih, const float* __restrict__ dWhh,
                          const float* __restrict__ dbih, const float* __restrict__ dbhh,
                          const float* __restrict__ oW, const float* __restrict__ ob,
                          float* __restrict__ out)
{
    __shared__ u32x4 sXT[2][6][64];   // per-wave x-ktile A-frags: [wave][3*tl+gate][lane]
    __shared__ u32x4 sEx[2][2][64];   // h-frag exchange: [parity][wave][lane]

    const int tid  = threadIdx.x;
    const int lane = tid & 63;
    const int w    = tid >> 6;        // wave id in team (0/1)
    const int c    = lane & 15;       // sample col
    const int g    = lane >> 4;       // lane group
    const long samp = (long)blockIdx.x * 16 + c;

    bfrag wr[2][2], wz[2][2], whn[2][2];   // [tl][j]: j=0 -> own kt(=w), j=1 -> other
    f32x4 bhn[2];                          // bhh n-rows (scaled), acc-init for aHN

    auto load_phase = [&](const float* __restrict__ Wih, const float* __restrict__ Whh,
                          const float* __restrict__ bih, const float* __restrict__ bhh) {
        __syncthreads();   // prior phase's sXT readers done
#pragma unroll
        for (int tl = 0; tl < 2; ++tl) {
            const int tt = 2 * w + tl;
            const int rowR = 16 * tt + c, rowZ = rowR + 64, rowN = rowR + 128;
#pragma unroll
            for (int j = 0; j < 2; ++j) {
                const int kt = (j == 0) ? w : 1 - w;
                bfrag fr, fz, fn;
#pragma unroll
                for (int e = 0; e < 8; ++e) {
                    const int k = 32 * kt + 16 * (e >> 2) + 4 * g + (e & 3);
                    fr[e] = f2bf(Whh[rowR * H_DIM + k] * S1);
                    fz[e] = f2bf(Whh[rowZ * H_DIM + k] * S1);
                    fn[e] = f2bf(Whh[rowN * H_DIM + k] * S2);
                }
                wr[tl][j] = fr; wz[tl][j] = fz; whn[tl][j] = fn;
            }
            bfrag xr, xz, xnw;   // x-ktile: k<8 = Wih, k==8 = bias row
#pragma unroll
            for (int e = 0; e < 8; ++e) {
                const int k = 16 * (e >> 2) + 4 * g + (e & 3);
                float vr = 0.f, vz = 0.f, vn = 0.f;
                if (k < F_DIM) {
                    vr = Wih[rowR * F_DIM + k]; vz = Wih[rowZ * F_DIM + k]; vn = Wih[rowN * F_DIM + k];
                } else if (k == F_DIM) {
                    vr = bih[rowR] + bhh[rowR]; vz = bih[rowZ] + bhh[rowZ]; vn = bih[rowN];
                }
                xr[e] = f2bf(vr * S1); xz[e] = f2bf(vz * S1); xnw[e] = f2bf(vn * S2);
            }
            sXT[w][3 * tl + 0][lane] = __builtin_bit_cast(u32x4, xr);
            sXT[w][3 * tl + 1][lane] = __builtin_bit_cast(u32x4, xz);
            sXT[w][3 * tl + 2][lane] = __builtin_bit_cast(u32x4, xnw);
#pragma unroll
            for (int r4 = 0; r4 < 4; ++r4) bhn[tl][r4] = bhh[128 + 16 * tt + 4 * g + r4] * S2;
        }
        __syncthreads();
    };

    f32x4 hc[2] = {{0.f, 0.f, 0.f, 0.f}, {0.f, 0.f, 0.f, 0.f}};
    bfrag hl = (bfrag){0, 0, 0, 0, 0, 0, 0, 0};   // own k-tile h-frag (kt = w)
    bfrag ho = (bfrag){0, 0, 0, 0, 0, 0, 0, 0};   // partner k-tile h-frag
    bfrag bx0 = (bfrag){0, 0, 0, 0, 0, 0, 0, 0};  // x-frag template: ones row at k==8 (g==2,e==0)
    if (g == 2) bx0[0] = f2bf(1.f);

    const u32x4* xt = &sXT[w][0][lane];

    auto step = [&](const bfrag bx) {
#pragma unroll
        for (int tl = 0; tl < 2; ++tl) {
            const bfrag xr  = __builtin_bit_cast(bfrag, xt[(3 * tl + 0) * 64]);
            const bfrag xz  = __builtin_bit_cast(bfrag, xt[(3 * tl + 1) * 64]);
            const bfrag xnw = __builtin_bit_cast(bfrag, xt[(3 * tl + 2) * 64]);
            f32x4 aR = {0.f, 0.f, 0.f, 0.f}, aZ = {0.f, 0.f, 0.f, 0.f};
            f32x4 aIN = {0.f, 0.f, 0.f, 0.f};
            f32x4 aHN = bhn[tl];                       // bias via acc-init
            aR = MFMA16(wr[tl][0], hl, aR);  aR = MFMA16(wr[tl][1], ho, aR);  aR = MFMA16(xr, bx, aR);
            aZ = MFMA16(wz[tl][0], hl, aZ);  aZ = MFMA16(wz[tl][1], ho, aZ);  aZ = MFMA16(xz, bx, aZ);
            aHN = MFMA16(whn[tl][0], hl, aHN); aHN = MFMA16(whn[tl][1], ho, aHN);
            aIN = MFMA16(xnw, bx, aIN);
#pragma unroll
            for (int r4 = 0; r4 < 4; ++r4) {
                // pre-activations arrive pre-scaled by log2e (r,z) / 2log2e (n)
                const float rg = __builtin_amdgcn_rcpf(1.f + __builtin_amdgcn_exp2f(-aR[r4]));
                const float zg = __builtin_amdgcn_rcpf(1.f + __builtin_amdgcn_exp2f(-aZ[r4]));
                const float np = aIN[r4] + rg * aHN[r4];
                const float ng = 1.f - 2.f * __builtin_amdgcn_rcpf(__builtin_amdgcn_exp2f(np) + 1.f);
                hc[tl][r4] = ng + zg * (hc[tl][r4] - ng);
            }
        }
        bfrag nl;
#pragma unroll
        for (int e = 0; e < 8; ++e) nl[e] = f2bf(hc[e >> 2][e & 3]);
        hl = nl;
    };

    // ================= encoder =================
    load_phase(eWih, eWhh, ebih, ebhh);
    int p = 0;
    const unsigned istep = B_SIZE * F_DIM * 4;
    unsigned ioff = (unsigned)((samp * F_DIM + 4 * g) * 4);
    float4 xn = make_float4(0.f, 0.f, 0.f, 0.f);
    if (g < 2) xn = ld4((const char*)inputs + ioff);
    ioff += istep;
#pragma unroll 1
    for (int t = 0; t < T_STEPS; ++t) {
        const float4 xv = xn;
        if (g < 2 && t + 1 < T_STEPS) xn = ld4((const char*)inputs + ioff);
        ioff += istep;
        bfrag bx = bx0;
        if (g < 2) { bx[0] = f2bf(xv.x); bx[1] = f2bf(xv.y); bx[2] = f2bf(xv.z); bx[3] = f2bf(xv.w); }
        step(bx);
        sEx[p][w][lane] = __builtin_bit_cast(u32x4, hl);
        __syncthreads();
        ho = __builtin_bit_cast(bfrag, sEx[p][w ^ 1][lane]);
        p ^= 1;
    }

    // ================= decoder =================
    load_phase(dWih, dWhh, dbih, dbhh);
    bfrag wo[2];   // out-proj A-frags (used by wave 0): j=0 <-> kt0(=hl for w0), j=1 <-> kt1
    f32x4 obv;
#pragma unroll
    for (int j = 0; j < 2; ++j)
#pragma unroll
        for (int e = 0; e < 8; ++e) {
            const int k = 32 * j + 16 * (e >> 2) + 4 * g + (e & 3);
            wo[j][e] = f2bf((c < F_DIM) ? oW[c * H_DIM + k] : 0.f);
        }
#pragma unroll
    for (int r4 = 0; r4 < 4; ++r4) obv[r4] = (g < 2) ? ob[4 * g + r4] : 0.f;

    unsigned toff = (unsigned)((samp * F_DIM + 4 * g) * 4);
    unsigned ooff = toff;
    xn = make_float4(0.f, 0.f, 0.f, 0.f);   // teacher forcing: x_0 = 0
#pragma unroll 1
    for (int t = 0; t < T_STEPS; ++t) {
        const float4 xv = xn;
        if (g < 2 && t + 1 < T_STEPS) xn = ld4((const char*)target + toff);  // x_{t+1} = target[t]
        toff += istep;
        bfrag bx = bx0;
        if (g < 2) { bx[0] = f2bf(xv.x); bx[1] = f2bf(xv.y); bx[2] = f2bf(xv.z); bx[3] = f2bf(xv.w); }
        step(bx);
        sEx[p][w][lane] = __builtin_bit_cast(u32x4, hl);
        __syncthreads();
        ho = __builtin_bit_cast(bfrag, sEx[p][w ^ 1][lane]);
        p ^= 1;
        if (w == 0) {   // y = h_new @ oW^T + ob ; C row = f(=4g+r, g<2), col = sample
            f32x4 aO = obv;
            aO = MFMA16(wo[0], hl, aO);
            aO = MFMA16(wo[1], ho, aO);
            if (g < 2) {
                float4 o; o.x = aO[0]; o.y = aO[1]; o.z = aO[2]; o.w = aO[3];
                *(float4*)((char*)out + ooff) = o;
            }
        }
        ooff += istep;
    }
}

extern "C" void kernel_launch(void* const* d_in, const int* in_sizes, int n_in,
                              void* d_out, int out_size, void* d_ws, size_t ws_size,
                              hipStream_t stream) {
    (void)in_sizes; (void)n_in; (void)d_ws; (void)ws_size; (void)out_size;
    const float* inputs = (const float*)d_in[0];
    const float* target = (const float*)d_in[1];
    const float* eWih   = (const float*)d_in[2];
    const float* eWhh   = (const float*)d_in[3];
    const float* ebih   = (const float*)d_in[4];
    const float* ebhh   = (const float*)d_in[5];
    const float* dWih   = (const float*)d_in[6];
    const float* dWhh   = (const float*)d_in[7];
    const float* dbih   = (const float*)d_in[8];
    const float* dbhh   = (const float*)d_in[9];
    const float* oW     = (const float*)d_in[10];
    const float* ob     = (const float*)d_in[11];
    float* out = (float*)d_out;

    seq2seq_split_kernel<<<dim3(GRID_BLOCKS), dim3(BLOCK_THREADS), 0, stream>>>(
        inputs, target, eWih, eWhh, ebih, ebhh, dWih, dWhh, dbih, dbhh, oW, ob, out);
}